// Round 2
// baseline (412.571 us; speedup 1.0000x reference)
//
#include <hip/hip_runtime.h>
#include <math.h>

#define KK 48
#define TT 1024
#define BB 512
#define START_TAG 46
#define END_TAG 47

// ---------------------------------------------------------------------------
// Single fused kernel: forward algorithm + gold score, one wave per sentence.
//
// Linear-domain recurrence: alpha'[i] = (sum_j E[i,j]*alpha[j]) * exp(feat[t,i])
// with E = exp(trans) precomputed in VGPRs (row i in lane i) and alpha held
// WAVE-UNIFORM in SGPRs: after each step, 48 v_readlane broadcasts pull the
// new alpha out of the lanes into SGPRs, and the next step's 48 FMAs consume
// them via the one-SGPR-operand slot. No LDS in the loop at all (R1 showed
// 12x ds_read_b128 issue = ~144 cyc/step, the dominant cost).
//
// Uniform power-of-2 rescale every 4 steps, exponent tracked exactly in an
// int ledger (absmax was 0.0 with this scheme in R1).
// exp(-1e5) == 0 handles the START-row / END-col masking automatically.
// ---------------------------------------------------------------------------
__global__ __launch_bounds__(64) void crf_kernel(const float* __restrict__ feats,
                                                 const float* __restrict__ trans,
                                                 const int* __restrict__ tags,
                                                 float* __restrict__ out) {
    const int b = blockIdx.x;
    const int i = threadIdx.x;
    const int ci = (i < KK) ? i : 0;   // clamped lane->tag (avoids OOB loads)
    const float* fb = feats + (size_t)b * TT * KK;
    const int* tg = tags + b * TT;

    // ---- gold (numerator) gather: 16 t's per lane, independent loads ----
    float gacc = 0.0f;
    #pragma unroll 4
    for (int t = i; t < TT; t += 64) {
        int cur = tg[t];
        int prev = (t == 0) ? START_TAG : tg[t - 1];
        gacc += trans[cur * KK + prev] + fb[t * KK + cur];
    }
    {
        // trans[END, tags[T-1]] folded in once (lane 0 only)
        if (i == 0) gacc += trans[END_TAG * KK + tg[TT - 1]];
    }

    // ---- E row i in registers: E[j] = exp(trans[i][j]) ----
    float E[KK];
    #pragma unroll
    for (int j = 0; j < KK; ++j) E[j] = __expf(trans[ci * KK + j]);
    const float eEND = __expf(trans[END_TAG * KK + ci]);

    // ---- alpha, wave-uniform (SGPRs) ----
    float a_u[KK];
    #pragma unroll
    for (int j = 0; j < KK; ++j) a_u[j] = (j == START_TAG) ? 1.0f : 0.0f;

    int esum = 0;          // exact power-of-2 scaling ledger
    float sLast = 0.0f;

    // feats prefetch: group of 4 steps, load next group while processing current
    float fr[4];
    #pragma unroll
    for (int k = 0; k < 4; ++k) fr[k] = fb[k * KK + ci];

    for (int g = 0; g < TT / 4; ++g) {
        float fn[4] = {0.f, 0.f, 0.f, 0.f};
        if (g < TT / 4 - 1) {
            #pragma unroll
            for (int k = 0; k < 4; ++k) fn[k] = fb[((g + 1) * 4 + k) * KK + ci];
        }
        // exp(feat) for current group — raw values loaded a group ago
        float ef[4];
        #pragma unroll
        for (int k = 0; k < 4; ++k) ef[k] = __expf(fr[k]);

        #pragma unroll
        for (int k = 0; k < 4; ++k) {
            // matvec: lane i computes s_i = sum_j E[i,j] * a_u[j]
            // 4 interleaved accumulator chains to keep FMA dep latency hidden
            float a0 = 0.f, a1 = 0.f, a2 = 0.f, a3 = 0.f;
            #pragma unroll
            for (int c = 0; c < 12; ++c) {
                a0 = fmaf(E[4 * c + 0], a_u[4 * c + 0], a0);
                a1 = fmaf(E[4 * c + 1], a_u[4 * c + 1], a1);
                a2 = fmaf(E[4 * c + 2], a_u[4 * c + 2], a2);
                a3 = fmaf(E[4 * c + 3], a_u[4 * c + 3], a3);
            }
            float s = (a0 + a1) + (a2 + a3);
            s *= ef[k];

            // uniform power-of-2 rescale once per group; a_u[0] (previous
            // alpha, strictly positive from step 1 on) is already uniform
            if (k == 1) {
                int e0 = ((__float_as_int(a_u[0]) >> 23) & 0xff) - 127;
                esum += e0;
                s *= __int_as_float((127 - e0) << 23);   // * 2^-e0, exact
            }
            sLast = s;

            // broadcast new alpha into SGPRs: 48 readlanes
            int sbits = __float_as_int(s);
            #pragma unroll
            for (int j = 0; j < KK; ++j)
                a_u[j] = __int_as_float(__builtin_amdgcn_readlane(sbits, j));
        }
        #pragma unroll
        for (int k = 0; k < 4; ++k) fr[k] = fn[k];
    }

    // ---- epilogue: log_z and output ----
    float val = (i < KK) ? sLast * eEND : 0.0f;
    #pragma unroll
    for (int off = 32; off; off >>= 1) {
        val += __shfl_xor(val, off, 64);
        gacc += __shfl_xor(gacc, off, 64);
    }

    if (i == 0) {
        float logz = __logf(val) + (float)esum * 0.6931471805599453f;
        out[b] = logz - gacc;
    }
}

extern "C" void kernel_launch(void* const* d_in, const int* in_sizes, int n_in,
                              void* d_out, int out_size, void* d_ws, size_t ws_size,
                              hipStream_t stream) {
    const float* feats = (const float*)d_in[0];
    const float* trans = (const float*)d_in[1];
    const int* tags = (const int*)d_in[2];
    float* out = (float*)d_out;

    crf_kernel<<<BB, 64, 0, stream>>>(feats, trans, tags, out);
}

// Round 3
// 410.316 us; speedup vs baseline: 1.0055x; 1.0055x over previous
//
#include <hip/hip_runtime.h>
#include <math.h>

#define KK 48
#define TT 1024
#define BB 512
#define START_TAG 46
#define END_TAG 47

// ---------------------------------------------------------------------------
// Single fused kernel: forward algorithm + gold score, one wave per sentence.
//
// Linear-domain recurrence: alpha'[i] = (sum_j E[i,j]*alpha[j]) * exp(feat[t,i])
// with E = exp(trans) in VGPRs (row i in lane i) and alpha WAVE-UNIFORM in
// SGPRs via 48 v_readlane broadcasts per step. No LDS in the loop.
//
// KEY FIX vs R2: __launch_bounds__(64, 1). Without the min-waves arg the
// allocator capped arch-VGPRs at 32 and evicted E[48] to AGPR/scratch
// (R2: VGPR_Count=32, FETCH_SIZE +32MB of scratch traffic, 730 cyc/step).
// This kernel is chain-latency-bound at 0.5 waves/SIMD — occupancy is
// worthless, registers are not.
//
// Uniform power-of-2 rescale every 4 steps, exponent tracked exactly in an
// int ledger (absmax 0.0 in R1/R2). exp(-1e5)==0 handles START-row/END-col
// masking automatically.
// ---------------------------------------------------------------------------
__global__ __launch_bounds__(64, 1) void crf_kernel(const float* __restrict__ feats,
                                                    const float* __restrict__ trans,
                                                    const int* __restrict__ tags,
                                                    float* __restrict__ out) {
    const int b = blockIdx.x;
    const int i = threadIdx.x;
    const int ci = (i < KK) ? i : 0;   // clamped lane->tag (avoids OOB loads)
    const float* fb = feats + (size_t)b * TT * KK;
    const int* tg = tags + b * TT;

    // ---- gold (numerator) gather: 16 t's per lane, independent loads ----
    float gacc = 0.0f;
    #pragma unroll 4
    for (int t = i; t < TT; t += 64) {
        int cur = tg[t];
        int prev = (t == 0) ? START_TAG : tg[t - 1];
        gacc += trans[cur * KK + prev] + fb[t * KK + cur];
    }
    if (i == 0) gacc += trans[END_TAG * KK + tg[TT - 1]];

    // ---- E row i in registers: E[j] = exp(trans[i][j]) ----
    float E[KK];
    #pragma unroll
    for (int j = 0; j < KK; ++j) E[j] = __expf(trans[ci * KK + j]);
    const float eEND = __expf(trans[END_TAG * KK + ci]);

    // ---- alpha, wave-uniform (SGPRs via readlane) ----
    float a_u[KK];
    #pragma unroll
    for (int j = 0; j < KK; ++j) a_u[j] = (j == START_TAG) ? 1.0f : 0.0f;

    int esum = 0;          // exact power-of-2 scaling ledger
    float sLast = 0.0f;

    // feats prefetch: group of 4 steps, load next group while processing current
    float fr[4];
    #pragma unroll
    for (int k = 0; k < 4; ++k) fr[k] = fb[k * KK + ci];

    for (int g = 0; g < TT / 4; ++g) {
        float fn[4] = {0.f, 0.f, 0.f, 0.f};
        if (g < TT / 4 - 1) {
            #pragma unroll
            for (int k = 0; k < 4; ++k) fn[k] = fb[((g + 1) * 4 + k) * KK + ci];
        }
        // exp(feat) for current group — raw values loaded a group ago
        float ef[4];
        #pragma unroll
        for (int k = 0; k < 4; ++k) ef[k] = __expf(fr[k]);

        #pragma unroll
        for (int k = 0; k < 4; ++k) {
            // matvec: lane i computes s_i = sum_j E[i,j] * a_u[j]
            // 4 interleaved accumulator chains; each fma_j only needs a_u[j],
            // so the scheduler can interleave with the readlanes below.
            float a0 = 0.f, a1 = 0.f, a2 = 0.f, a3 = 0.f;
            #pragma unroll
            for (int c = 0; c < 12; ++c) {
                a0 = fmaf(E[4 * c + 0], a_u[4 * c + 0], a0);
                a1 = fmaf(E[4 * c + 1], a_u[4 * c + 1], a1);
                a2 = fmaf(E[4 * c + 2], a_u[4 * c + 2], a2);
                a3 = fmaf(E[4 * c + 3], a_u[4 * c + 3], a3);
            }
            float s = (a0 + a1) + (a2 + a3);
            s *= ef[k];

            // uniform power-of-2 rescale once per group; a_u[0] (previous
            // alpha, strictly positive from step 1 on) is already uniform
            if (k == 1) {
                int e0 = ((__float_as_int(a_u[0]) >> 23) & 0xff) - 127;
                esum += e0;
                s *= __int_as_float((127 - e0) << 23);   // * 2^-e0, exact
            }
            sLast = s;

            // broadcast new alpha into SGPRs: 48 readlanes of the same VGPR
            int sbits = __float_as_int(s);
            #pragma unroll
            for (int j = 0; j < KK; ++j)
                a_u[j] = __int_as_float(__builtin_amdgcn_readlane(sbits, j));
        }
        #pragma unroll
        for (int k = 0; k < 4; ++k) fr[k] = fn[k];
    }

    // ---- epilogue: log_z and output ----
    float val = (i < KK) ? sLast * eEND : 0.0f;
    #pragma unroll
    for (int off = 32; off; off >>= 1) {
        val += __shfl_xor(val, off, 64);
        gacc += __shfl_xor(gacc, off, 64);
    }

    if (i == 0) {
        float logz = __logf(val) + (float)esum * 0.6931471805599453f;
        out[b] = logz - gacc;
    }
}

extern "C" void kernel_launch(void* const* d_in, const int* in_sizes, int n_in,
                              void* d_out, int out_size, void* d_ws, size_t ws_size,
                              hipStream_t stream) {
    const float* feats = (const float*)d_in[0];
    const float* trans = (const float*)d_in[1];
    const int* tags = (const int*)d_in[2];
    float* out = (float*)d_out;

    crf_kernel<<<BB, 64, 0, stream>>>(feats, trans, tags, out);
}